// Round 1
// baseline (1142.412 us; speedup 1.0000x reference)
//
#include <hip/hip_runtime.h>

// ---------------------------------------------------------------------------
// MultiScaleFeatureFusion — restructured:
//   scale0: x1 [4,512,16,16]  d=64 C=512 hs=16 Ns=256  R=2d+1+32=161
//   scale1: x2 [4,256,32,32]  d=32 C=256 hs=32 Ns=1024 R=97
//   scale2: x3 [4,128,64,64]  d=16 C=128 hs=64 Ns=4096 R=65
// Per scale we pack rows [wq(d), wk(d), u=wa^T wv (1), w1-slice(32)] into one
// matrix, run one projection GEMM at NATIVE resolution, bilinearly upsample
// only the q/k/s rows to 64x64, then flash-style softmax attention with a
// SCALAR value s[m] per position (a[n] = softmax(q_n.k_m) . s + ba).
// Final: out[n] = sum_j w2[j]*relu(prod[n]*G[j,n]+b1[j]) + b2, with G from the
// three small GEMM outputs + on-the-fly bilinear.
// ---------------------------------------------------------------------------

#define BB 4

static constexpr int OFF_WP0 = 0;                       // 161*512
static constexpr int OFF_WP1 = OFF_WP0 + 161 * 512;     // 97*256
static constexpr int OFF_WP2 = OFF_WP1 + 97 * 256;      // 65*128
static constexpr int OFF_B0  = OFF_WP2 + 65 * 128;
static constexpr int OFF_B1  = OFF_B0 + 192;
static constexpr int OFF_B2  = OFF_B1 + 128;
static constexpr int OFF_PROJ0 = OFF_B2 + 96;
static constexpr int OFF_PROJ1 = OFF_PROJ0 + BB * 161 * 256;
static constexpr int OFF_PROJ2 = OFF_PROJ1 + BB * 97 * 1024;
static constexpr int OFF_BIG0  = OFF_PROJ2 + BB * 65 * 4096;   // [b][129][4096]
static constexpr int OFF_BIG1  = OFF_BIG0 + BB * 129 * 4096;   // [b][65][4096]
static constexpr int PS = BB * 8 * 4096;                       // partials per scale
static constexpr int OFF_PM  = OFF_BIG1 + BB * 65 * 4096;
static constexpr int OFF_PSN = OFF_PM + 3 * PS;
static constexpr int OFF_PSW = OFF_PSN + 3 * PS;
static constexpr int OFF_A   = OFF_PSW + 3 * PS;               // 3*B*4096

// --------------------------- pack kernel -----------------------------------
// One launch per scale; block per row r of Wpack [R, C].
__global__ void pack_kernel(const float* __restrict__ wq, const float* __restrict__ bq,
                            const float* __restrict__ wk, const float* __restrict__ bk,
                            const float* __restrict__ wv, const float* __restrict__ bv,
                            const float* __restrict__ wa,
                            const float* __restrict__ w1, int w1off,
                            float* __restrict__ wp, float* __restrict__ bias,
                            int C, int d) {
    int r = blockIdx.x;
    int tid = threadIdx.x;
    float* dst = wp + r * C;
    if (r < d) {
        for (int c = tid; c < C; c += blockDim.x) dst[c] = wq[r * C + c];
        if (tid == 0) bias[r] = bq[r];
    } else if (r < 2 * d) {
        int rr = r - d;
        for (int c = tid; c < C; c += blockDim.x) dst[c] = wk[rr * C + c];
        if (tid == 0) bias[r] = bk[rr];
    } else if (r == 2 * d) {
        for (int ci = tid; ci < C; ci += blockDim.x) {
            float acc = 0.f;
            for (int co = 0; co < C; ++co) acc += wa[co] * wv[co * C + ci];
            dst[ci] = acc;
        }
        if (tid == 0) {
            float acc = 0.f;
            for (int co = 0; co < C; ++co) acc += wa[co] * bv[co];
            bias[r] = acc;
        }
    } else {
        int j = r - (2 * d + 1);
        for (int c = tid; c < C; c += blockDim.x) dst[c] = w1[j * 896 + w1off + c];
        if (tid == 0) bias[r] = 0.f;
    }
}

// --------------------------- projection GEMM -------------------------------
// out[b, r, m] = sum_c Wpack[r,c] * x[b,c,m] + bias[r]
// block: 256 threads = one m-tile; 8 rows per block (rows staged in LDS).
__global__ __launch_bounds__(256) void proj_kernel(const float* __restrict__ x,
                                                   const float* __restrict__ wp,
                                                   const float* __restrict__ bias,
                                                   float* __restrict__ out,
                                                   int C, int Ns, int R) {
    __shared__ float Wl[8 * 512];
    __shared__ float bl[8];
    int b = blockIdx.z;
    int r0 = blockIdx.y * 8;
    int nr = min(8, R - r0);
    int tid = threadIdx.x;
    for (int rr = 0; rr < nr; ++rr)
        for (int c = tid; c < C; c += 256) Wl[rr * C + c] = wp[(r0 + rr) * C + c];
    if (tid < nr) bl[tid] = bias[r0 + tid];
    __syncthreads();
    int m = blockIdx.x * 256 + tid;
    float acc[8];
#pragma unroll
    for (int rr = 0; rr < 8; ++rr) acc[rr] = 0.f;
    const float* xb = x + (b * C) * Ns + m;
    for (int c = 0; c < C; ++c) {
        float xv = xb[c * Ns];
#pragma unroll
        for (int rr = 0; rr < 8; ++rr) acc[rr] += Wl[rr * C + c] * xv;
    }
    for (int rr = 0; rr < nr; ++rr)
        out[(b * R + r0 + rr) * Ns + m] = acc[rr] + bl[rr];
}

// --------------------------- upsample (q/k/s rows) -------------------------
__global__ void upsample_kernel(const float* __restrict__ proj, float* __restrict__ big,
                                int Rsrc, int nrows, int hs, int Ns) {
    int idx = blockIdx.x * 256 + threadIdx.x;
    int total = BB * nrows * 4096;
    if (idx >= total) return;
    int n = idx & 4095;
    int row = (idx >> 12) % nrows;
    int b = idx / (nrows * 4096);
    int oy = n >> 6, ox = n & 63;
    float f = (float)(hs - 1) / 63.0f;
    float cy = oy * f, cx = ox * f;
    int iy0 = min((int)floorf(cy), hs - 2);
    int ix0 = min((int)floorf(cx), hs - 2);
    float wy = cy - iy0, wx = cx - ix0;
    const float* ps = proj + (b * Rsrc + row) * Ns;
    float v00 = ps[iy0 * hs + ix0], v01 = ps[iy0 * hs + ix0 + 1];
    float v10 = ps[(iy0 + 1) * hs + ix0], v11 = ps[(iy0 + 1) * hs + ix0 + 1];
    float v = (1.f - wy) * ((1.f - wx) * v00 + wx * v01) + wy * ((1.f - wx) * v10 + wx * v11);
    big[(b * nrows + row) * 4096 + n] = v;
}

// --------------------------- attention -------------------------------------
// base layout per batch: rows [0,D)=q, [D,2D)=k, row 2D = s;  row stride 4096.
// grid (16 n-tiles, 8 m-chunks, B); thread = one n; online softmax over its
// 512-m chunk; partial (M, Sn, Sw) written for the combine kernel.
template <int D>
__global__ __launch_bounds__(256) void attn_kernel(const float* __restrict__ base, int bstride,
                                                   float* __restrict__ pM, float* __restrict__ pSn,
                                                   float* __restrict__ pSw) {
    __shared__ __align__(16) float kl[D * 128];
    __shared__ float sl[128];
    int tid = threadIdx.x;
    int b = blockIdx.z;
    int chunk = blockIdx.y;
    int n = blockIdx.x * 256 + tid;
    const float* bb = base + b * bstride;
    float qv[D];
#pragma unroll
    for (int dd = 0; dd < D; ++dd) qv[dd] = bb[dd * 4096 + n];
    float M = -1e30f, Sn = 0.f, Sw = 0.f;
    int m0 = chunk * 512;
    for (int mt = 0; mt < 512; mt += 128) {
        __syncthreads();
        for (int idx = tid; idx < D * 128; idx += 256) {
            int dd = idx >> 7, mm = idx & 127;
            kl[idx] = bb[(D + dd) * 4096 + m0 + mt + mm];
        }
        if (tid < 128) sl[tid] = bb[2 * D * 4096 + m0 + mt + tid];
        __syncthreads();
        for (int mm = 0; mm < 128; mm += 4) {
            float l0 = 0.f, l1 = 0.f, l2 = 0.f, l3 = 0.f;
#pragma unroll
            for (int dd = 0; dd < D; ++dd) {
                float4 kv = *(const float4*)&kl[dd * 128 + mm];
                float q = qv[dd];
                l0 += q * kv.x; l1 += q * kv.y; l2 += q * kv.z; l3 += q * kv.w;
            }
            float lm = fmaxf(fmaxf(l0, l1), fmaxf(l2, l3));
            float Mn = fmaxf(M, lm);
            float sc = __expf(M - Mn);
            Sn *= sc; Sw *= sc;
            float e0 = __expf(l0 - Mn), e1 = __expf(l1 - Mn);
            float e2 = __expf(l2 - Mn), e3 = __expf(l3 - Mn);
            Sn += e0 + e1 + e2 + e3;
            Sw += e0 * sl[mm] + e1 * sl[mm + 1] + e2 * sl[mm + 2] + e3 * sl[mm + 3];
            M = Mn;
        }
    }
    int pidx = (b * 8 + chunk) * 4096 + n;
    pM[pidx] = M; pSn[pidx] = Sn; pSw[pidx] = Sw;
}

// --------------------------- combine partials ------------------------------
__global__ void combine_kernel(const float* __restrict__ pMb, const float* __restrict__ pSnb,
                               const float* __restrict__ pSwb,
                               const float* __restrict__ ba0, const float* __restrict__ ba1,
                               const float* __restrict__ ba2, float* __restrict__ a) {
    int s = blockIdx.y;
    const float* pM = pMb + s * PS;
    const float* pSn = pSnb + s * PS;
    const float* pSw = pSwb + s * PS;
    const float* bap = (s == 0) ? ba0 : (s == 1) ? ba1 : ba2;
    int idx = blockIdx.x * 256 + threadIdx.x;  // b*4096+n
    int b = idx >> 12, n = idx & 4095;
    float M = -1e30f;
#pragma unroll
    for (int ch = 0; ch < 8; ++ch) M = fmaxf(M, pM[(b * 8 + ch) * 4096 + n]);
    float Sn = 0.f, Sw = 0.f;
#pragma unroll
    for (int ch = 0; ch < 8; ++ch) {
        int pi = (b * 8 + ch) * 4096 + n;
        float sc = __expf(pM[pi] - M);
        Sn += pSn[pi] * sc;
        Sw += pSw[pi] * sc;
    }
    a[s * BB * 4096 + idx] = Sw / Sn + bap[0];
}

// --------------------------- final fusion ----------------------------------
__global__ __launch_bounds__(256) void final_kernel(const float* __restrict__ proj0,
                                                    const float* __restrict__ proj1,
                                                    const float* __restrict__ proj2,
                                                    const float* __restrict__ a,
                                                    const float* __restrict__ b1,
                                                    const float* __restrict__ w2,
                                                    const float* __restrict__ b2,
                                                    float* __restrict__ out) {
    __shared__ float lb1[32], lw2[32];
    int tid = threadIdx.x;
    if (tid < 32) { lb1[tid] = b1[tid]; lw2[tid] = w2[tid]; }
    __syncthreads();
    int b = blockIdx.y;
    int n = blockIdx.x * 256 + tid;  // 0..4095
    int oy = n >> 6, ox = n & 63;
    float prod = a[(0 * BB + b) * 4096 + n] * a[(1 * BB + b) * 4096 + n] *
                 a[(2 * BB + b) * 4096 + n];
    // scale0 grid 16x16
    float f0 = 15.0f / 63.0f;
    float cy0 = oy * f0, cx0 = ox * f0;
    int iy0 = min((int)floorf(cy0), 14), ix0 = min((int)floorf(cx0), 14);
    float wy0 = cy0 - iy0, wx0 = cx0 - ix0;
    // scale1 grid 32x32
    float f1 = 31.0f / 63.0f;
    float cy1 = oy * f1, cx1 = ox * f1;
    int iy1 = min((int)floorf(cy1), 30), ix1 = min((int)floorf(cx1), 30);
    float wy1 = cy1 - iy1, wx1 = cx1 - ix1;
    const float* g0b = proj0 + (b * 161 + 129) * 256;   // 32 rows, 16x16 each
    const float* g1b = proj1 + (b * 97 + 65) * 1024;    // 32 rows, 32x32 each
    const float* g2b = proj2 + (b * 65 + 33) * 4096;    // 32 rows, 64x64 each
    float outv = 0.f;
    for (int j = 0; j < 32; ++j) {
        const float* p0 = g0b + j * 256;
        float v0 = (1.f - wy0) * ((1.f - wx0) * p0[iy0 * 16 + ix0] + wx0 * p0[iy0 * 16 + ix0 + 1]) +
                   wy0 * ((1.f - wx0) * p0[(iy0 + 1) * 16 + ix0] + wx0 * p0[(iy0 + 1) * 16 + ix0 + 1]);
        const float* p1 = g1b + j * 1024;
        float v1 = (1.f - wy1) * ((1.f - wx1) * p1[iy1 * 32 + ix1] + wx1 * p1[iy1 * 32 + ix1 + 1]) +
                   wy1 * ((1.f - wx1) * p1[(iy1 + 1) * 32 + ix1] + wx1 * p1[(iy1 + 1) * 32 + ix1 + 1]);
        float g = g2b[j * 4096 + n] + v0 + v1;
        float h = fmaxf(prod * g + lb1[j], 0.f);
        outv += lw2[j] * h;
    }
    out[b * 4096 + n] = outv + b2[0];
}

// ---------------------------------------------------------------------------
extern "C" void kernel_launch(void* const* d_in, const int* in_sizes, int n_in,
                              void* d_out, int out_size, void* d_ws, size_t ws_size,
                              hipStream_t stream) {
    const float* x3 = (const float*)d_in[0];
    const float* x2 = (const float*)d_in[1];
    const float* x1 = (const float*)d_in[2];
    // per-scale attention weights: base = 3 + i*8
    const float* wq[3]; const float* bq[3]; const float* wk[3]; const float* bk[3];
    const float* wv[3]; const float* bv[3]; const float* wa[3]; const float* ba[3];
    for (int i = 0; i < 3; ++i) {
        wq[i] = (const float*)d_in[3 + 8 * i + 0];
        bq[i] = (const float*)d_in[3 + 8 * i + 1];
        wk[i] = (const float*)d_in[3 + 8 * i + 2];
        bk[i] = (const float*)d_in[3 + 8 * i + 3];
        wv[i] = (const float*)d_in[3 + 8 * i + 4];
        bv[i] = (const float*)d_in[3 + 8 * i + 5];
        wa[i] = (const float*)d_in[3 + 8 * i + 6];
        ba[i] = (const float*)d_in[3 + 8 * i + 7];
    }
    const float* w1 = (const float*)d_in[27];
    const float* b1 = (const float*)d_in[28];
    const float* w2 = (const float*)d_in[29];
    const float* b2 = (const float*)d_in[30];
    float* ws = (float*)d_ws;
    float* out = (float*)d_out;

    // pack (scale s: weight index s; s0 uses x1/C=512, s1 x2/C=256, s2 x3/C=128)
    pack_kernel<<<161, 256, 0, stream>>>(wq[0], bq[0], wk[0], bk[0], wv[0], bv[0], wa[0],
                                         w1, 384, ws + OFF_WP0, ws + OFF_B0, 512, 64);
    pack_kernel<<<97, 256, 0, stream>>>(wq[1], bq[1], wk[1], bk[1], wv[1], bv[1], wa[1],
                                        w1, 128, ws + OFF_WP1, ws + OFF_B1, 256, 32);
    pack_kernel<<<65, 256, 0, stream>>>(wq[2], bq[2], wk[2], bk[2], wv[2], bv[2], wa[2],
                                        w1, 0, ws + OFF_WP2, ws + OFF_B2, 128, 16);

    // projection GEMMs at native resolution
    proj_kernel<<<dim3(1, 21, BB), 256, 0, stream>>>(x1, ws + OFF_WP0, ws + OFF_B0,
                                                     ws + OFF_PROJ0, 512, 256, 161);
    proj_kernel<<<dim3(4, 13, BB), 256, 0, stream>>>(x2, ws + OFF_WP1, ws + OFF_B1,
                                                     ws + OFF_PROJ1, 256, 1024, 97);
    proj_kernel<<<dim3(16, 9, BB), 256, 0, stream>>>(x3, ws + OFF_WP2, ws + OFF_B2,
                                                     ws + OFF_PROJ2, 128, 4096, 65);

    // upsample q/k/s rows (scale0: 129 rows, scale1: 65 rows)
    upsample_kernel<<<(BB * 129 * 4096 + 255) / 256, 256, 0, stream>>>(
        ws + OFF_PROJ0, ws + OFF_BIG0, 161, 129, 16, 256);
    upsample_kernel<<<(BB * 65 * 4096 + 255) / 256, 256, 0, stream>>>(
        ws + OFF_PROJ1, ws + OFF_BIG1, 97, 65, 32, 1024);

    // attention (flash-style, m-split x8)
    attn_kernel<64><<<dim3(16, 8, BB), 256, 0, stream>>>(
        ws + OFF_BIG0, 129 * 4096, ws + OFF_PM + 0 * PS, ws + OFF_PSN + 0 * PS, ws + OFF_PSW + 0 * PS);
    attn_kernel<32><<<dim3(16, 8, BB), 256, 0, stream>>>(
        ws + OFF_BIG1, 65 * 4096, ws + OFF_PM + 1 * PS, ws + OFF_PSN + 1 * PS, ws + OFF_PSW + 1 * PS);
    attn_kernel<16><<<dim3(16, 8, BB), 256, 0, stream>>>(
        ws + OFF_PROJ2, 65 * 4096, ws + OFF_PM + 2 * PS, ws + OFF_PSN + 2 * PS, ws + OFF_PSW + 2 * PS);

    // combine partials -> a[s][b][n] (+ba)
    combine_kernel<<<dim3(64, 3), 256, 0, stream>>>(ws + OFF_PM, ws + OFF_PSN, ws + OFF_PSW,
                                                    ba[0], ba[1], ba[2], ws + OFF_A);

    // final fusion
    final_kernel<<<dim3(16, BB), 256, 0, stream>>>(ws + OFF_PROJ0, ws + OFF_PROJ1, ws + OFF_PROJ2,
                                                   ws + OFF_A, b1, w2, b2, out);
}

// Round 2
// 615.984 us; speedup vs baseline: 1.8546x; 1.8546x over previous
//
#include <hip/hip_runtime.h>

// ---------------------------------------------------------------------------
// MultiScaleFeatureFusion — restructured:
//   scale0: x1 [4,512,16,16]  d=64 C=512 hs=16 Ns=256  R=2d+1+32=161
//   scale1: x2 [4,256,32,32]  d=32 C=256 hs=32 Ns=1024 R=97
//   scale2: x3 [4,128,64,64]  d=16 C=128 hs=64 Ns=4096 R=65
// Pack rows [wq(d), wk(d), u=wa^T wv (1), w1-slice(32)], project at NATIVE
// resolution, upsample only q/k/s rows, flash-attention with SCALAR value.
// R2 changes: parallel u_kernel (was 423us serial-latency block); attention
// register-blocked NB=2 (ds_read_b128 amortized over 8 FMAs), 16 chunks.
// ---------------------------------------------------------------------------

#define BB 4
static constexpr int NC = 16;   // m-chunks per scale

static constexpr int OFF_WP0 = 0;                       // 161*512
static constexpr int OFF_WP1 = OFF_WP0 + 161 * 512;     // 97*256
static constexpr int OFF_WP2 = OFF_WP1 + 97 * 256;      // 65*128
static constexpr int OFF_B0  = OFF_WP2 + 65 * 128;
static constexpr int OFF_B1  = OFF_B0 + 192;
static constexpr int OFF_B2  = OFF_B1 + 128;
static constexpr int OFF_PROJ0 = OFF_B2 + 96;
static constexpr int OFF_PROJ1 = OFF_PROJ0 + BB * 161 * 256;
static constexpr int OFF_PROJ2 = OFF_PROJ1 + BB * 97 * 1024;
static constexpr int OFF_BIG0  = OFF_PROJ2 + BB * 65 * 4096;   // [b][129][4096]
static constexpr int OFF_BIG1  = OFF_BIG0 + BB * 129 * 4096;   // [b][65][4096]
static constexpr int PS = BB * NC * 4096;                      // partials per scale
static constexpr int OFF_PM  = OFF_BIG1 + BB * 65 * 4096;
static constexpr int OFF_PSN = OFF_PM + 3 * PS;
static constexpr int OFF_PSW = OFF_PSN + 3 * PS;
static constexpr int OFF_A   = OFF_PSW + 3 * PS;               // 3*B*4096

// --------------------------- pack kernel -----------------------------------
// Block per row r of Wpack [R, C]; row 2d handled by u_kernel instead.
__global__ void pack_kernel(const float* __restrict__ wq, const float* __restrict__ bq,
                            const float* __restrict__ wk, const float* __restrict__ bk,
                            const float* __restrict__ w1, int w1off,
                            float* __restrict__ wp, float* __restrict__ bias,
                            int C, int d) {
    int r = blockIdx.x;
    int tid = threadIdx.x;
    float* dst = wp + r * C;
    if (r < d) {
        for (int c = tid; c < C; c += blockDim.x) dst[c] = wq[r * C + c];
        if (tid == 0) bias[r] = bq[r];
    } else if (r < 2 * d) {
        int rr = r - d;
        for (int c = tid; c < C; c += blockDim.x) dst[c] = wk[rr * C + c];
        if (tid == 0) bias[r] = bk[rr];
    } else if (r == 2 * d) {
        return;  // filled by u_kernel
    } else {
        int j = r - (2 * d + 1);
        for (int c = tid; c < C; c += blockDim.x) dst[c] = w1[j * 896 + w1off + c];
        if (tid == 0) bias[r] = 0.f;
    }
}

// --------------------------- u = wa^T wv (parallel) ------------------------
// grid C/64 blocks x 256 threads: 64 ci per block, 4 co-strips, LDS reduce.
__global__ void u_kernel(const float* __restrict__ wv, const float* __restrict__ wa,
                         const float* __restrict__ bv,
                         float* __restrict__ urow, float* __restrict__ ubias, int C) {
    __shared__ float red[256];
    int tid = threadIdx.x;
    int lci = tid & 63;
    int strip = tid >> 6;         // wave-uniform
    int ci = blockIdx.x * 64 + lci;
    float acc = 0.f;
#pragma unroll 4
    for (int co = strip; co < C; co += 4)
        acc += wa[co] * wv[co * C + ci];
    red[tid] = acc;
    __syncthreads();
    if (strip == 0)
        urow[ci] = red[lci] + red[lci + 64] + red[lci + 128] + red[lci + 192];
    if (blockIdx.x == 0) {
        __syncthreads();
        float bacc = 0.f;
        for (int co = tid; co < C; co += 256) bacc += wa[co] * bv[co];
        red[tid] = bacc;
        __syncthreads();
        for (int off = 128; off > 0; off >>= 1) {
            if (tid < off) red[tid] += red[tid + off];
            __syncthreads();
        }
        if (tid == 0) *ubias = red[0];
    }
}

// --------------------------- projection GEMM -------------------------------
__global__ __launch_bounds__(256) void proj_kernel(const float* __restrict__ x,
                                                   const float* __restrict__ wp,
                                                   const float* __restrict__ bias,
                                                   float* __restrict__ out,
                                                   int C, int Ns, int R) {
    __shared__ float Wl[8 * 512];
    __shared__ float bl[8];
    int b = blockIdx.z;
    int r0 = blockIdx.y * 8;
    int nr = min(8, R - r0);
    int tid = threadIdx.x;
    for (int rr = 0; rr < nr; ++rr)
        for (int c = tid; c < C; c += 256) Wl[rr * C + c] = wp[(r0 + rr) * C + c];
    if (tid < nr) bl[tid] = bias[r0 + tid];
    __syncthreads();
    int m = blockIdx.x * 256 + tid;
    float acc[8];
#pragma unroll
    for (int rr = 0; rr < 8; ++rr) acc[rr] = 0.f;
    const float* xb = x + (b * C) * Ns + m;
    for (int c = 0; c < C; ++c) {
        float xv = xb[c * Ns];
#pragma unroll
        for (int rr = 0; rr < 8; ++rr) acc[rr] += Wl[rr * C + c] * xv;
    }
    for (int rr = 0; rr < nr; ++rr)
        out[(b * R + r0 + rr) * Ns + m] = acc[rr] + bl[rr];
}

// --------------------------- upsample (q/k/s rows) -------------------------
__global__ void upsample_kernel(const float* __restrict__ proj, float* __restrict__ big,
                                int Rsrc, int nrows, int hs, int Ns) {
    int idx = blockIdx.x * 256 + threadIdx.x;
    int total = BB * nrows * 4096;
    if (idx >= total) return;
    int n = idx & 4095;
    int row = (idx >> 12) % nrows;
    int b = idx / (nrows * 4096);
    int oy = n >> 6, ox = n & 63;
    float f = (float)(hs - 1) / 63.0f;
    float cy = oy * f, cx = ox * f;
    int iy0 = min((int)floorf(cy), hs - 2);
    int ix0 = min((int)floorf(cx), hs - 2);
    float wy = cy - iy0, wx = cx - ix0;
    const float* ps = proj + (b * Rsrc + row) * Ns;
    float v00 = ps[iy0 * hs + ix0], v01 = ps[iy0 * hs + ix0 + 1];
    float v10 = ps[(iy0 + 1) * hs + ix0], v11 = ps[(iy0 + 1) * hs + ix0 + 1];
    float v = (1.f - wy) * ((1.f - wx) * v00 + wx * v01) + wy * ((1.f - wx) * v10 + wx * v11);
    big[(b * nrows + row) * 4096 + n] = v;
}

// --------------------------- attention (NB=2) ------------------------------
// base rows per batch: [0,D)=q, [D,2D)=k, row 2D=s; row stride 4096.
// grid (8 n-tiles, NC chunks, B); thread owns n0=tile*512+tid and n1=n0+256.
// 256-m chunk, two 128-m LDS tiles; online softmax; partials for combine.
template <int D>
__global__ __launch_bounds__(256, 2) void attn_kernel(const float* __restrict__ base, int bstride,
                                                      float* __restrict__ pM,
                                                      float* __restrict__ pSn,
                                                      float* __restrict__ pSw) {
    __shared__ __align__(16) float kl[D * 128];
    __shared__ __align__(16) float sl[128];
    int tid = threadIdx.x;
    int b = blockIdx.z;
    int chunk = blockIdx.y;
    int n0 = blockIdx.x * 512 + tid;
    const float* bb = base + b * bstride;
    float qv0[D], qv1[D];
#pragma unroll
    for (int dd = 0; dd < D; ++dd) {
        qv0[dd] = bb[dd * 4096 + n0];
        qv1[dd] = bb[dd * 4096 + n0 + 256];
    }
    float M0 = -1e30f, Sn0 = 0.f, Sw0 = 0.f;
    float M1 = -1e30f, Sn1 = 0.f, Sw1 = 0.f;
    int m0 = chunk * 256;
    for (int mt = 0; mt < 256; mt += 128) {
        __syncthreads();
        constexpr int NF4 = D * 128 / 4;
        int mbase = m0 + mt;
        for (int fi = tid; fi < NF4; fi += 256) {
            int dd = fi >> 5;
            int mm = (fi << 2) & 127;
            *(float4*)&kl[fi << 2] = *(const float4*)&bb[(D + dd) * 4096 + mbase + mm];
        }
        if (tid < 32)
            *(float4*)&sl[tid * 4] = *(const float4*)&bb[2 * D * 4096 + mbase + tid * 4];
        __syncthreads();
        for (int mm = 0; mm < 128; mm += 4) {
            float l00 = 0.f, l01 = 0.f, l02 = 0.f, l03 = 0.f;
            float l10 = 0.f, l11 = 0.f, l12 = 0.f, l13 = 0.f;
#pragma unroll
            for (int dd = 0; dd < D; ++dd) {
                float4 kv = *(const float4*)&kl[dd * 128 + mm];
                float q0 = qv0[dd], q1 = qv1[dd];
                l00 += q0 * kv.x; l01 += q0 * kv.y; l02 += q0 * kv.z; l03 += q0 * kv.w;
                l10 += q1 * kv.x; l11 += q1 * kv.y; l12 += q1 * kv.z; l13 += q1 * kv.w;
            }
            float4 sv = *(const float4*)&sl[mm];
            {
                float lm = fmaxf(fmaxf(l00, l01), fmaxf(l02, l03));
                float Mn = fmaxf(M0, lm);
                float sc = __expf(M0 - Mn);
                float e0 = __expf(l00 - Mn), e1 = __expf(l01 - Mn);
                float e2 = __expf(l02 - Mn), e3 = __expf(l03 - Mn);
                Sn0 = Sn0 * sc + e0 + e1 + e2 + e3;
                Sw0 = Sw0 * sc + e0 * sv.x + e1 * sv.y + e2 * sv.z + e3 * sv.w;
                M0 = Mn;
            }
            {
                float lm = fmaxf(fmaxf(l10, l11), fmaxf(l12, l13));
                float Mn = fmaxf(M1, lm);
                float sc = __expf(M1 - Mn);
                float e0 = __expf(l10 - Mn), e1 = __expf(l11 - Mn);
                float e2 = __expf(l12 - Mn), e3 = __expf(l13 - Mn);
                Sn1 = Sn1 * sc + e0 + e1 + e2 + e3;
                Sw1 = Sw1 * sc + e0 * sv.x + e1 * sv.y + e2 * sv.z + e3 * sv.w;
                M1 = Mn;
            }
        }
    }
    int pidx0 = (b * NC + chunk) * 4096 + n0;
    pM[pidx0] = M0; pSn[pidx0] = Sn0; pSw[pidx0] = Sw0;
    int pidx1 = pidx0 + 256;
    pM[pidx1] = M1; pSn[pidx1] = Sn1; pSw[pidx1] = Sw1;
}

// --------------------------- combine partials ------------------------------
__global__ void combine_kernel(const float* __restrict__ pMb, const float* __restrict__ pSnb,
                               const float* __restrict__ pSwb,
                               const float* __restrict__ ba0, const float* __restrict__ ba1,
                               const float* __restrict__ ba2, float* __restrict__ a) {
    int s = blockIdx.y;
    const float* pM = pMb + s * PS;
    const float* pSn = pSnb + s * PS;
    const float* pSw = pSwb + s * PS;
    const float* bap = (s == 0) ? ba0 : (s == 1) ? ba1 : ba2;
    int idx = blockIdx.x * 256 + threadIdx.x;  // b*4096+n
    int b = idx >> 12, n = idx & 4095;
    float M = -1e30f;
#pragma unroll
    for (int ch = 0; ch < NC; ++ch) M = fmaxf(M, pM[(b * NC + ch) * 4096 + n]);
    float Sn = 0.f, Sw = 0.f;
#pragma unroll
    for (int ch = 0; ch < NC; ++ch) {
        int pi = (b * NC + ch) * 4096 + n;
        float sc = __expf(pM[pi] - M);
        Sn += pSn[pi] * sc;
        Sw += pSw[pi] * sc;
    }
    a[s * BB * 4096 + idx] = Sw / Sn + bap[0];
}

// --------------------------- final fusion ----------------------------------
__global__ __launch_bounds__(256) void final_kernel(const float* __restrict__ proj0,
                                                    const float* __restrict__ proj1,
                                                    const float* __restrict__ proj2,
                                                    const float* __restrict__ a,
                                                    const float* __restrict__ b1,
                                                    const float* __restrict__ w2,
                                                    const float* __restrict__ b2,
                                                    float* __restrict__ out) {
    __shared__ float lb1[32], lw2[32];
    int tid = threadIdx.x;
    if (tid < 32) { lb1[tid] = b1[tid]; lw2[tid] = w2[tid]; }
    __syncthreads();
    int b = blockIdx.y;
    int n = blockIdx.x * 256 + tid;  // 0..4095
    int oy = n >> 6, ox = n & 63;
    float prod = a[(0 * BB + b) * 4096 + n] * a[(1 * BB + b) * 4096 + n] *
                 a[(2 * BB + b) * 4096 + n];
    float f0 = 15.0f / 63.0f;
    float cy0 = oy * f0, cx0 = ox * f0;
    int iy0 = min((int)floorf(cy0), 14), ix0 = min((int)floorf(cx0), 14);
    float wy0 = cy0 - iy0, wx0 = cx0 - ix0;
    float f1 = 31.0f / 63.0f;
    float cy1 = oy * f1, cx1 = ox * f1;
    int iy1 = min((int)floorf(cy1), 30), ix1 = min((int)floorf(cx1), 30);
    float wy1 = cy1 - iy1, wx1 = cx1 - ix1;
    const float* g0b = proj0 + (b * 161 + 129) * 256;   // 32 rows, 16x16 each
    const float* g1b = proj1 + (b * 97 + 65) * 1024;    // 32 rows, 32x32 each
    const float* g2b = proj2 + (b * 65 + 33) * 4096;    // 32 rows, 64x64 each
    float outv = 0.f;
    for (int j = 0; j < 32; ++j) {
        const float* p0 = g0b + j * 256;
        float v0 = (1.f - wy0) * ((1.f - wx0) * p0[iy0 * 16 + ix0] + wx0 * p0[iy0 * 16 + ix0 + 1]) +
                   wy0 * ((1.f - wx0) * p0[(iy0 + 1) * 16 + ix0] + wx0 * p0[(iy0 + 1) * 16 + ix0 + 1]);
        const float* p1 = g1b + j * 1024;
        float v1 = (1.f - wy1) * ((1.f - wx1) * p1[iy1 * 32 + ix1] + wx1 * p1[iy1 * 32 + ix1 + 1]) +
                   wy1 * ((1.f - wx1) * p1[(iy1 + 1) * 32 + ix1] + wx1 * p1[(iy1 + 1) * 32 + ix1 + 1]);
        float g = g2b[j * 4096 + n] + v0 + v1;
        float h = fmaxf(prod * g + lb1[j], 0.f);
        outv += lw2[j] * h;
    }
    out[b * 4096 + n] = outv + b2[0];
}

// ---------------------------------------------------------------------------
extern "C" void kernel_launch(void* const* d_in, const int* in_sizes, int n_in,
                              void* d_out, int out_size, void* d_ws, size_t ws_size,
                              hipStream_t stream) {
    const float* x3 = (const float*)d_in[0];
    const float* x2 = (const float*)d_in[1];
    const float* x1 = (const float*)d_in[2];
    const float* wq[3]; const float* bq[3]; const float* wk[3]; const float* bk[3];
    const float* wv[3]; const float* bv[3]; const float* wa[3]; const float* ba[3];
    for (int i = 0; i < 3; ++i) {
        wq[i] = (const float*)d_in[3 + 8 * i + 0];
        bq[i] = (const float*)d_in[3 + 8 * i + 1];
        wk[i] = (const float*)d_in[3 + 8 * i + 2];
        bk[i] = (const float*)d_in[3 + 8 * i + 3];
        wv[i] = (const float*)d_in[3 + 8 * i + 4];
        bv[i] = (const float*)d_in[3 + 8 * i + 5];
        wa[i] = (const float*)d_in[3 + 8 * i + 6];
        ba[i] = (const float*)d_in[3 + 8 * i + 7];
    }
    const float* w1 = (const float*)d_in[27];
    const float* b1 = (const float*)d_in[28];
    const float* w2 = (const float*)d_in[29];
    const float* b2 = (const float*)d_in[30];
    float* ws = (float*)d_ws;
    float* out = (float*)d_out;

    // pack q/k/w1 rows
    pack_kernel<<<161, 256, 0, stream>>>(wq[0], bq[0], wk[0], bk[0],
                                         w1, 384, ws + OFF_WP0, ws + OFF_B0, 512, 64);
    pack_kernel<<<97, 256, 0, stream>>>(wq[1], bq[1], wk[1], bk[1],
                                        w1, 128, ws + OFF_WP1, ws + OFF_B1, 256, 32);
    pack_kernel<<<65, 256, 0, stream>>>(wq[2], bq[2], wk[2], bk[2],
                                        w1, 0, ws + OFF_WP2, ws + OFF_B2, 128, 16);
    // u = wa^T wv rows (parallel)
    u_kernel<<<8, 256, 0, stream>>>(wv[0], wa[0], bv[0],
                                    ws + OFF_WP0 + 128 * 512, ws + OFF_B0 + 128, 512);
    u_kernel<<<4, 256, 0, stream>>>(wv[1], wa[1], bv[1],
                                    ws + OFF_WP1 + 64 * 256, ws + OFF_B1 + 64, 256);
    u_kernel<<<2, 256, 0, stream>>>(wv[2], wa[2], bv[2],
                                    ws + OFF_WP2 + 32 * 128, ws + OFF_B2 + 32, 128);

    // projection GEMMs at native resolution
    proj_kernel<<<dim3(1, 21, BB), 256, 0, stream>>>(x1, ws + OFF_WP0, ws + OFF_B0,
                                                     ws + OFF_PROJ0, 512, 256, 161);
    proj_kernel<<<dim3(4, 13, BB), 256, 0, stream>>>(x2, ws + OFF_WP1, ws + OFF_B1,
                                                     ws + OFF_PROJ1, 256, 1024, 97);
    proj_kernel<<<dim3(16, 9, BB), 256, 0, stream>>>(x3, ws + OFF_WP2, ws + OFF_B2,
                                                     ws + OFF_PROJ2, 128, 4096, 65);

    // upsample q/k/s rows
    upsample_kernel<<<(BB * 129 * 4096 + 255) / 256, 256, 0, stream>>>(
        ws + OFF_PROJ0, ws + OFF_BIG0, 161, 129, 16, 256);
    upsample_kernel<<<(BB * 65 * 4096 + 255) / 256, 256, 0, stream>>>(
        ws + OFF_PROJ1, ws + OFF_BIG1, 97, 65, 32, 1024);

    // attention
    attn_kernel<64><<<dim3(8, NC, BB), 256, 0, stream>>>(
        ws + OFF_BIG0, 129 * 4096, ws + OFF_PM + 0 * PS, ws + OFF_PSN + 0 * PS, ws + OFF_PSW + 0 * PS);
    attn_kernel<32><<<dim3(8, NC, BB), 256, 0, stream>>>(
        ws + OFF_BIG1, 65 * 4096, ws + OFF_PM + 1 * PS, ws + OFF_PSN + 1 * PS, ws + OFF_PSW + 1 * PS);
    attn_kernel<16><<<dim3(8, NC, BB), 256, 0, stream>>>(
        ws + OFF_PROJ2, 65 * 4096, ws + OFF_PM + 2 * PS, ws + OFF_PSN + 2 * PS, ws + OFF_PSW + 2 * PS);

    // combine partials -> a[s][b][n] (+ba)
    combine_kernel<<<dim3(64, 3), 256, 0, stream>>>(ws + OFF_PM, ws + OFF_PSN, ws + OFF_PSW,
                                                    ba[0], ba[1], ba[2], ws + OFF_A);

    // final fusion
    final_kernel<<<dim3(16, BB), 256, 0, stream>>>(ws + OFF_PROJ0, ws + OFF_PROJ1, ws + OFF_PROJ2,
                                                   ws + OFF_A, b1, w2, b2, out);
}